// Round 1
// baseline (450.389 us; speedup 1.0000x reference)
//
#include <hip/hip_runtime.h>
#include <hip/hip_bf16.h>

// Problem constants
constexpr int DIM_ = 1024;
constexpr int H_   = 16;
constexpr int D_   = 64;
constexpr int HID_ = 1024;   // H_*D_
constexpr int N_   = 2;
constexpr int T_   = 1024;
constexpr int MTOT = N_ * T_;   // 2048 rows

// ---------------------------------------------------------------------------
// GEMM 1: fused QKV.  C[m,n] = sum_k x[m,k]*W(n)[k]  for n in [0,3072)
//   n <  1024 : W = key_w[n],       out = sigmoid(val + key_b[n]) -> Kb
//   n >= 1024 : W = vq_w[n-1024]    (v for n<2048 -> Vb, q otherwise -> Qb)
// 64x64 tile, K-step 16, 256 threads, 4x4 micro-tile per thread.
// ---------------------------------------------------------------------------
__global__ __launch_bounds__(256) void gemm_qkv(
    const float* __restrict__ x,
    const float* __restrict__ key_w,
    const float* __restrict__ key_b,
    const float* __restrict__ vq_w,
    float* __restrict__ Kb,
    float* __restrict__ Vb,
    float* __restrict__ Qb)
{
    __shared__ float As[16][68];   // pad 4 floats: keeps 16B alignment, no conflicts
    __shared__ float Ws[16][68];

    const int N0 = blockIdx.x * 64;      // 0..3071
    const int M0 = blockIdx.y * 64;      // 0..2047
    const int tid = threadIdx.x;
    const int tx = tid & 15;             // n-sub
    const int ty = tid >> 4;             // m-sub
    const int lr = tid >> 2;             // 0..63 load row
    const int lk = (tid & 3) * 4;        // 0,4,8,12 load k-offset

    const float* Wbase;
    int nOff;
    if (N0 < HID_) { Wbase = key_w; nOff = N0; }
    else           { Wbase = vq_w;  nOff = N0 - HID_; }

    float acc[4][4] = {};

    for (int k0 = 0; k0 < DIM_; k0 += 16) {
        float4 a4 = *(const float4*)(x     + (size_t)(M0   + lr) * DIM_ + k0 + lk);
        float4 w4 = *(const float4*)(Wbase + (size_t)(nOff + lr) * DIM_ + k0 + lk);
        __syncthreads();
        As[lk + 0][lr] = a4.x; As[lk + 1][lr] = a4.y;
        As[lk + 2][lr] = a4.z; As[lk + 3][lr] = a4.w;
        Ws[lk + 0][lr] = w4.x; Ws[lk + 1][lr] = w4.y;
        Ws[lk + 2][lr] = w4.z; Ws[lk + 3][lr] = w4.w;
        __syncthreads();
        #pragma unroll
        for (int kk = 0; kk < 16; ++kk) {
            float4 av = *(const float4*)&As[kk][ty * 4];
            float4 wv = *(const float4*)&Ws[kk][tx * 4];
            float a[4] = {av.x, av.y, av.z, av.w};
            float w[4] = {wv.x, wv.y, wv.z, wv.w};
            #pragma unroll
            for (int i = 0; i < 4; ++i)
                #pragma unroll
                for (int j = 0; j < 4; ++j)
                    acc[i][j] += a[i] * w[j];
        }
    }

    const int nBase = N0 + tx * 4;
    if (N0 < HID_) {
        float b0 = key_b[nBase + 0], b1 = key_b[nBase + 1];
        float b2 = key_b[nBase + 2], b3 = key_b[nBase + 3];
        #pragma unroll
        for (int i = 0; i < 4; ++i) {
            int m = M0 + ty * 4 + i;
            float4 o;
            o.x = 1.f / (1.f + expf(-(acc[i][0] + b0)));
            o.y = 1.f / (1.f + expf(-(acc[i][1] + b1)));
            o.z = 1.f / (1.f + expf(-(acc[i][2] + b2)));
            o.w = 1.f / (1.f + expf(-(acc[i][3] + b3)));
            *(float4*)(Kb + (size_t)m * HID_ + nBase) = o;
        }
    } else if (N0 < 2 * HID_) {
        #pragma unroll
        for (int i = 0; i < 4; ++i) {
            int m = M0 + ty * 4 + i;
            float4 o = {acc[i][0], acc[i][1], acc[i][2], acc[i][3]};
            *(float4*)(Vb + (size_t)m * HID_ + (nBase - HID_)) = o;
        }
    } else {
        #pragma unroll
        for (int i = 0; i < 4; ++i) {
            int m = M0 + ty * 4 + i;
            float4 o = {acc[i][0], acc[i][1], acc[i][2], acc[i][3]};
            *(float4*)(Qb + (size_t)m * HID_ + (nBase - 2 * HID_)) = o;
        }
    }
}

// ---------------------------------------------------------------------------
// Recurrent scan per (n, head):  kv[d][e] = k[d]*kv[d][e] + (1-k[d])*v[e]
//                                h[e]    += q[d]*kv[d][e]   (sum over d)
// Block = 256 threads = 4 waves. Wave w owns d in [w*16, w*16+16); lane = e.
// kv state: 16 regs/thread. h reduced across the 4 waves once per 32-step chunk.
// ---------------------------------------------------------------------------
constexpr int CH = 32;
__global__ __launch_bounds__(256) void scan_kernel(
    const float* __restrict__ Kb,
    const float* __restrict__ Vb,
    const float* __restrict__ Qb,
    float* __restrict__ Hb)
{
    __shared__ float sk[CH][64];
    __shared__ float sv[CH][64];
    __shared__ float sq[CH][64];
    __shared__ float hp[4][CH][64];

    const int tid  = threadIdx.x;
    const int w    = tid >> 6;
    const int lane = tid & 63;
    const int head = blockIdx.x;          // 0..31
    const int n = head >> 4, h = head & 15;
    const size_t base = ((size_t)n * T_) * HID_ + (size_t)h * 64;

    float kv[16];
    #pragma unroll
    for (int i = 0; i < 16; ++i) kv[i] = 0.f;

    for (int t0 = 0; t0 < T_; t0 += CH) {
        __syncthreads();   // previous chunk fully consumed before re-staging
        #pragma unroll
        for (int i = 0; i < CH * 64 / 256; ++i) {   // 8 iters
            int idx = tid + i * 256;
            int tl = idx >> 6, d = idx & 63;
            size_t g = base + (size_t)(t0 + tl) * HID_ + d;
            sk[tl][d] = Kb[g];
            sv[tl][d] = Vb[g];
            sq[tl][d] = Qb[g];
        }
        __syncthreads();

        for (int tl = 0; tl < CH; ++tl) {
            float part = 0.f;
            float v = sv[tl][lane];
            #pragma unroll
            for (int i4 = 0; i4 < 4; ++i4) {
                float4 k4 = *(const float4*)&sk[tl][w * 16 + i4 * 4];
                float4 q4 = *(const float4*)&sq[tl][w * 16 + i4 * 4];
                float ks[4] = {k4.x, k4.y, k4.z, k4.w};
                float qs[4] = {q4.x, q4.y, q4.z, q4.w};
                #pragma unroll
                for (int j = 0; j < 4; ++j) {
                    int i = i4 * 4 + j;
                    kv[i] = ks[j] * kv[i] + (1.f - ks[j]) * v;
                    part += qs[j] * kv[i];
                }
            }
            hp[w][tl][lane] = part;
        }
        __syncthreads();

        #pragma unroll
        for (int i = 0; i < CH * 64 / 256; ++i) {
            int idx = tid + i * 256;
            int tl = idx >> 6, e = idx & 63;
            float s = hp[0][tl][e] + hp[1][tl][e] + hp[2][tl][e] + hp[3][tl][e];
            Hb[base + (size_t)(t0 + tl) * HID_ + e] = s;
        }
    }
}

// ---------------------------------------------------------------------------
// GEMM 2: out[m,n] = sum_e h[m,e]*out_w[n,e] + out_b[n]   (M=2048,N=1024,K=1024)
// ---------------------------------------------------------------------------
__global__ __launch_bounds__(256) void gemm_out(
    const float* __restrict__ Hb,
    const float* __restrict__ out_w,
    const float* __restrict__ out_b,
    float* __restrict__ Out)
{
    __shared__ float As[16][68];
    __shared__ float Ws[16][68];

    const int N0 = blockIdx.x * 64;
    const int M0 = blockIdx.y * 64;
    const int tid = threadIdx.x;
    const int tx = tid & 15;
    const int ty = tid >> 4;
    const int lr = tid >> 2;
    const int lk = (tid & 3) * 4;

    float acc[4][4] = {};

    for (int k0 = 0; k0 < HID_; k0 += 16) {
        float4 a4 = *(const float4*)(Hb    + (size_t)(M0 + lr) * HID_ + k0 + lk);
        float4 w4 = *(const float4*)(out_w + (size_t)(N0 + lr) * HID_ + k0 + lk);
        __syncthreads();
        As[lk + 0][lr] = a4.x; As[lk + 1][lr] = a4.y;
        As[lk + 2][lr] = a4.z; As[lk + 3][lr] = a4.w;
        Ws[lk + 0][lr] = w4.x; Ws[lk + 1][lr] = w4.y;
        Ws[lk + 2][lr] = w4.z; Ws[lk + 3][lr] = w4.w;
        __syncthreads();
        #pragma unroll
        for (int kk = 0; kk < 16; ++kk) {
            float4 av = *(const float4*)&As[kk][ty * 4];
            float4 wv = *(const float4*)&Ws[kk][tx * 4];
            float a[4] = {av.x, av.y, av.z, av.w};
            float w[4] = {wv.x, wv.y, wv.z, wv.w};
            #pragma unroll
            for (int i = 0; i < 4; ++i)
                #pragma unroll
                for (int j = 0; j < 4; ++j)
                    acc[i][j] += a[i] * w[j];
        }
    }

    const int nBase = N0 + tx * 4;
    float b0 = out_b[nBase + 0], b1 = out_b[nBase + 1];
    float b2 = out_b[nBase + 2], b3 = out_b[nBase + 3];
    #pragma unroll
    for (int i = 0; i < 4; ++i) {
        int m = M0 + ty * 4 + i;
        float4 o = {acc[i][0] + b0, acc[i][1] + b1, acc[i][2] + b2, acc[i][3] + b3};
        *(float4*)(Out + (size_t)m * DIM_ + nBase) = o;
    }
}

// ---------------------------------------------------------------------------
extern "C" void kernel_launch(void* const* d_in, const int* in_sizes, int n_in,
                              void* d_out, int out_size, void* d_ws, size_t ws_size,
                              hipStream_t stream)
{
    const float* x     = (const float*)d_in[0];
    const float* key_w = (const float*)d_in[1];
    const float* key_b = (const float*)d_in[2];
    const float* vq_w  = (const float*)d_in[3];
    const float* out_w = (const float*)d_in[4];
    const float* out_b = (const float*)d_in[5];
    float* out = (float*)d_out;

    // workspace layout: Kb | Vb | Qb | Hb, each MTOT*HID_ fp32 (8 MB) = 32 MB
    float* Kb = (float*)d_ws;
    float* Vb = Kb + (size_t)MTOT * HID_;
    float* Qb = Vb + (size_t)MTOT * HID_;
    float* Hb = Qb + (size_t)MTOT * HID_;

    gemm_qkv<<<dim3(48, 32), 256, 0, stream>>>(x, key_w, key_b, vq_w, Kb, Vb, Qb);
    scan_kernel<<<32, 256, 0, stream>>>(Kb, Vb, Qb, Hb);
    gemm_out<<<dim3(16, 32), 256, 0, stream>>>(Hb, out_w, out_b, out);
}

// Round 2
// 302.921 us; speedup vs baseline: 1.4868x; 1.4868x over previous
//
#include <hip/hip_runtime.h>
#include <hip/hip_bf16.h>

// Problem constants
constexpr int DIM_ = 1024;
constexpr int H_   = 16;
constexpr int D_   = 64;
constexpr int HID_ = 1024;   // H_*D_
constexpr int N_   = 2;
constexpr int T_   = 1024;
constexpr int MTOT = N_ * T_;   // 2048 rows

// scan chunking
constexpr int L_  = 64;          // chunk length
constexpr int C_  = T_ / L_;     // 16 chunks
constexpr int CH  = 32;          // LDS staging sub-chunk

// ---------------------------------------------------------------------------
// GEMM 1: fused QKV.  C[m,n] = sum_k x[m,k]*W(n)[k]  for n in [0,3072)
// ---------------------------------------------------------------------------
__global__ __launch_bounds__(256) void gemm_qkv(
    const float* __restrict__ x,
    const float* __restrict__ key_w,
    const float* __restrict__ key_b,
    const float* __restrict__ vq_w,
    float* __restrict__ Kb,
    float* __restrict__ Vb,
    float* __restrict__ Qb)
{
    __shared__ float As[16][68];
    __shared__ float Ws[16][68];

    const int N0 = blockIdx.x * 64;
    const int M0 = blockIdx.y * 64;
    const int tid = threadIdx.x;
    const int tx = tid & 15;
    const int ty = tid >> 4;
    const int lr = tid >> 2;
    const int lk = (tid & 3) * 4;

    const float* Wbase;
    int nOff;
    if (N0 < HID_) { Wbase = key_w; nOff = N0; }
    else           { Wbase = vq_w;  nOff = N0 - HID_; }

    float acc[4][4] = {};

    for (int k0 = 0; k0 < DIM_; k0 += 16) {
        float4 a4 = *(const float4*)(x     + (size_t)(M0   + lr) * DIM_ + k0 + lk);
        float4 w4 = *(const float4*)(Wbase + (size_t)(nOff + lr) * DIM_ + k0 + lk);
        __syncthreads();
        As[lk + 0][lr] = a4.x; As[lk + 1][lr] = a4.y;
        As[lk + 2][lr] = a4.z; As[lk + 3][lr] = a4.w;
        Ws[lk + 0][lr] = w4.x; Ws[lk + 1][lr] = w4.y;
        Ws[lk + 2][lr] = w4.z; Ws[lk + 3][lr] = w4.w;
        __syncthreads();
        #pragma unroll
        for (int kk = 0; kk < 16; ++kk) {
            float4 av = *(const float4*)&As[kk][ty * 4];
            float4 wv = *(const float4*)&Ws[kk][tx * 4];
            float a[4] = {av.x, av.y, av.z, av.w};
            float w[4] = {wv.x, wv.y, wv.z, wv.w};
            #pragma unroll
            for (int i = 0; i < 4; ++i)
                #pragma unroll
                for (int j = 0; j < 4; ++j)
                    acc[i][j] += a[i] * w[j];
        }
    }

    const int nBase = N0 + tx * 4;
    if (N0 < HID_) {
        float b0 = key_b[nBase + 0], b1 = key_b[nBase + 1];
        float b2 = key_b[nBase + 2], b3 = key_b[nBase + 3];
        #pragma unroll
        for (int i = 0; i < 4; ++i) {
            int m = M0 + ty * 4 + i;
            float4 o;
            o.x = 1.f / (1.f + expf(-(acc[i][0] + b0)));
            o.y = 1.f / (1.f + expf(-(acc[i][1] + b1)));
            o.z = 1.f / (1.f + expf(-(acc[i][2] + b2)));
            o.w = 1.f / (1.f + expf(-(acc[i][3] + b3)));
            *(float4*)(Kb + (size_t)m * HID_ + nBase) = o;
        }
    } else if (N0 < 2 * HID_) {
        #pragma unroll
        for (int i = 0; i < 4; ++i) {
            int m = M0 + ty * 4 + i;
            float4 o = {acc[i][0], acc[i][1], acc[i][2], acc[i][3]};
            *(float4*)(Vb + (size_t)m * HID_ + (nBase - HID_)) = o;
        }
    } else {
        #pragma unroll
        for (int i = 0; i < 4; ++i) {
            int m = M0 + ty * 4 + i;
            float4 o = {acc[i][0], acc[i][1], acc[i][2], acc[i][3]};
            *(float4*)(Qb + (size_t)m * HID_ + (nBase - 2 * HID_)) = o;
        }
    }
}

// ---------------------------------------------------------------------------
// Scan phase 1: per (n,h,c) chunk, scan from zero state.
// Emits B_c[d,e] (chunk-local end state) into Sbuf and P_c[d] = prod k into Pbuf.
// Block: 256 thr = 4 waves; wave w owns d in [w*16,w*16+16), lane = e.
// ---------------------------------------------------------------------------
__global__ __launch_bounds__(256) void scan_phase1(
    const float* __restrict__ Kb,
    const float* __restrict__ Vb,
    float* __restrict__ Sbuf,
    float* __restrict__ Pbuf)
{
    __shared__ float sk[CH][64];
    __shared__ float sv[CH][64];

    const int tid  = threadIdx.x;
    const int w    = tid >> 6;
    const int lane = tid & 63;
    const int c    = blockIdx.x % C_;
    const int head = blockIdx.x / C_;      // 0..31
    const int n = head >> 4, h = head & 15;
    const size_t base = ((size_t)n * T_) * HID_ + (size_t)h * 64;

    float kv[16], p[16];
    #pragma unroll
    for (int i = 0; i < 16; ++i) { kv[i] = 0.f; p[i] = 1.f; }

    for (int t0 = c * L_; t0 < (c + 1) * L_; t0 += CH) {
        __syncthreads();
        #pragma unroll
        for (int i = 0; i < CH * 64 / 256; ++i) {
            int idx = tid + i * 256;
            int tl = idx >> 6, d = idx & 63;
            size_t g = base + (size_t)(t0 + tl) * HID_ + d;
            sk[tl][d] = Kb[g];
            sv[tl][d] = Vb[g];
        }
        __syncthreads();

        for (int tl = 0; tl < CH; ++tl) {
            float v = sv[tl][lane];
            #pragma unroll
            for (int i4 = 0; i4 < 4; ++i4) {
                float4 k4 = *(const float4*)&sk[tl][w * 16 + i4 * 4];
                float ks[4] = {k4.x, k4.y, k4.z, k4.w};
                #pragma unroll
                for (int j = 0; j < 4; ++j) {
                    int i = i4 * 4 + j;
                    kv[i] = ks[j] * kv[i] + (1.f - ks[j]) * v;
                    p[i] *= ks[j];
                }
            }
        }
    }

    const size_t sidx = ((size_t)(head * C_ + c)) * (D_ * D_) + (size_t)(w * 16) * D_ + lane;
    #pragma unroll
    for (int i = 0; i < 16; ++i) Sbuf[sidx + (size_t)i * D_] = kv[i];
    if (lane == 0) {
        const size_t pidx = (size_t)(head * C_ + c) * D_ + w * 16;
        #pragma unroll
        for (int i = 0; i < 16; ++i) Pbuf[pidx + i] = p[i];
    }
}

// ---------------------------------------------------------------------------
// Scan phase 2: serial combine over chunks (per (n,h)).
// Reads B_c from Sbuf, overwrites slot with S_init(c) (state BEFORE chunk c):
//   S_init(0)=0;  S <- P_c*S + B_c
// ---------------------------------------------------------------------------
__global__ __launch_bounds__(256) void scan_combine(
    float* __restrict__ Sbuf,
    const float* __restrict__ Pbuf)
{
    const int tid  = threadIdx.x;
    const int w    = tid >> 6;
    const int lane = tid & 63;
    const int head = blockIdx.x;

    float S[16];
    #pragma unroll
    for (int i = 0; i < 16; ++i) S[i] = 0.f;

    for (int c = 0; c < C_; ++c) {
        const size_t sidx = ((size_t)(head * C_ + c)) * (D_ * D_) + (size_t)(w * 16) * D_ + lane;
        const size_t pidx = (size_t)(head * C_ + c) * D_ + w * 16;
        #pragma unroll
        for (int i = 0; i < 16; ++i) {
            float B  = Sbuf[sidx + (size_t)i * D_];
            float pp = Pbuf[pidx + i];
            Sbuf[sidx + (size_t)i * D_] = S[i];
            S[i] = pp * S[i] + B;
        }
    }
}

// ---------------------------------------------------------------------------
// Scan phase 3: per (n,h,c) chunk, scan from S_init(c), compute h outputs.
// ---------------------------------------------------------------------------
__global__ __launch_bounds__(256) void scan_phase3(
    const float* __restrict__ Kb,
    const float* __restrict__ Vb,
    const float* __restrict__ Qb,
    const float* __restrict__ Sbuf,
    float* __restrict__ Hb)
{
    __shared__ float sk[CH][64];
    __shared__ float sv[CH][64];
    __shared__ float sq[CH][64];
    __shared__ float hp[4][CH][64];

    const int tid  = threadIdx.x;
    const int w    = tid >> 6;
    const int lane = tid & 63;
    const int c    = blockIdx.x % C_;
    const int head = blockIdx.x / C_;
    const int n = head >> 4, h = head & 15;
    const size_t base = ((size_t)n * T_) * HID_ + (size_t)h * 64;

    float kv[16];
    const size_t sidx = ((size_t)(head * C_ + c)) * (D_ * D_) + (size_t)(w * 16) * D_ + lane;
    #pragma unroll
    for (int i = 0; i < 16; ++i) kv[i] = Sbuf[sidx + (size_t)i * D_];

    for (int t0 = c * L_; t0 < (c + 1) * L_; t0 += CH) {
        __syncthreads();
        #pragma unroll
        for (int i = 0; i < CH * 64 / 256; ++i) {
            int idx = tid + i * 256;
            int tl = idx >> 6, d = idx & 63;
            size_t g = base + (size_t)(t0 + tl) * HID_ + d;
            sk[tl][d] = Kb[g];
            sv[tl][d] = Vb[g];
            sq[tl][d] = Qb[g];
        }
        __syncthreads();

        for (int tl = 0; tl < CH; ++tl) {
            float part = 0.f;
            float v = sv[tl][lane];
            #pragma unroll
            for (int i4 = 0; i4 < 4; ++i4) {
                float4 k4 = *(const float4*)&sk[tl][w * 16 + i4 * 4];
                float4 q4 = *(const float4*)&sq[tl][w * 16 + i4 * 4];
                float ks[4] = {k4.x, k4.y, k4.z, k4.w};
                float qs[4] = {q4.x, q4.y, q4.z, q4.w};
                #pragma unroll
                for (int j = 0; j < 4; ++j) {
                    int i = i4 * 4 + j;
                    kv[i] = ks[j] * kv[i] + (1.f - ks[j]) * v;
                    part += qs[j] * kv[i];
                }
            }
            hp[w][tl][lane] = part;
        }
        __syncthreads();

        #pragma unroll
        for (int i = 0; i < CH * 64 / 256; ++i) {
            int idx = tid + i * 256;
            int tl = idx >> 6, e = idx & 63;
            float s = hp[0][tl][e] + hp[1][tl][e] + hp[2][tl][e] + hp[3][tl][e];
            Hb[base + (size_t)(t0 + tl) * HID_ + e] = s;
        }
    }
}

// ---------------------------------------------------------------------------
// GEMM 2: out[m,n] = sum_e h[m,e]*out_w[n,e] + out_b[n]
// ---------------------------------------------------------------------------
__global__ __launch_bounds__(256) void gemm_out(
    const float* __restrict__ Hb,
    const float* __restrict__ out_w,
    const float* __restrict__ out_b,
    float* __restrict__ Out)
{
    __shared__ float As[16][68];
    __shared__ float Ws[16][68];

    const int N0 = blockIdx.x * 64;
    const int M0 = blockIdx.y * 64;
    const int tid = threadIdx.x;
    const int tx = tid & 15;
    const int ty = tid >> 4;
    const int lr = tid >> 2;
    const int lk = (tid & 3) * 4;

    float acc[4][4] = {};

    for (int k0 = 0; k0 < HID_; k0 += 16) {
        float4 a4 = *(const float4*)(Hb    + (size_t)(M0 + lr) * HID_ + k0 + lk);
        float4 w4 = *(const float4*)(out_w + (size_t)(N0 + lr) * HID_ + k0 + lk);
        __syncthreads();
        As[lk + 0][lr] = a4.x; As[lk + 1][lr] = a4.y;
        As[lk + 2][lr] = a4.z; As[lk + 3][lr] = a4.w;
        Ws[lk + 0][lr] = w4.x; Ws[lk + 1][lr] = w4.y;
        Ws[lk + 2][lr] = w4.z; Ws[lk + 3][lr] = w4.w;
        __syncthreads();
        #pragma unroll
        for (int kk = 0; kk < 16; ++kk) {
            float4 av = *(const float4*)&As[kk][ty * 4];
            float4 wv = *(const float4*)&Ws[kk][tx * 4];
            float a[4] = {av.x, av.y, av.z, av.w};
            float w[4] = {wv.x, wv.y, wv.z, wv.w};
            #pragma unroll
            for (int i = 0; i < 4; ++i)
                #pragma unroll
                for (int j = 0; j < 4; ++j)
                    acc[i][j] += a[i] * w[j];
        }
    }

    const int nBase = N0 + tx * 4;
    float b0 = out_b[nBase + 0], b1 = out_b[nBase + 1];
    float b2 = out_b[nBase + 2], b3 = out_b[nBase + 3];
    #pragma unroll
    for (int i = 0; i < 4; ++i) {
        int m = M0 + ty * 4 + i;
        float4 o = {acc[i][0] + b0, acc[i][1] + b1, acc[i][2] + b2, acc[i][3] + b3};
        *(float4*)(Out + (size_t)m * DIM_ + nBase) = o;
    }
}

// ---------------------------------------------------------------------------
extern "C" void kernel_launch(void* const* d_in, const int* in_sizes, int n_in,
                              void* d_out, int out_size, void* d_ws, size_t ws_size,
                              hipStream_t stream)
{
    const float* x     = (const float*)d_in[0];
    const float* key_w = (const float*)d_in[1];
    const float* key_b = (const float*)d_in[2];
    const float* vq_w  = (const float*)d_in[3];
    const float* out_w = (const float*)d_in[4];
    const float* out_b = (const float*)d_in[5];
    float* out = (float*)d_out;

    // workspace: Kb | Vb | Qb | Hb (8 MB each) | Sbuf (8 MB) | Pbuf (128 KB)
    float* Kb   = (float*)d_ws;
    float* Vb   = Kb + (size_t)MTOT * HID_;
    float* Qb   = Vb + (size_t)MTOT * HID_;
    float* Hb   = Qb + (size_t)MTOT * HID_;
    float* Sbuf = Hb + (size_t)MTOT * HID_;
    float* Pbuf = Sbuf + (size_t)N_ * H_ * C_ * D_ * D_;

    gemm_qkv<<<dim3(48, 32), 256, 0, stream>>>(x, key_w, key_b, vq_w, Kb, Vb, Qb);
    scan_phase1<<<N_ * H_ * C_, 256, 0, stream>>>(Kb, Vb, Sbuf, Pbuf);
    scan_combine<<<N_ * H_, 256, 0, stream>>>(Sbuf, Pbuf);
    scan_phase3<<<N_ * H_ * C_, 256, 0, stream>>>(Kb, Vb, Qb, Sbuf, Hb);
    gemm_out<<<dim3(16, 32), 256, 0, stream>>>(Hb, out_w, out_b, out);
}

// Round 3
// 109.218 us; speedup vs baseline: 4.1237x; 2.7735x over previous
//
#include <hip/hip_runtime.h>
#include <hip/hip_bf16.h>

typedef __attribute__((ext_vector_type(8))) short short8;
typedef __attribute__((ext_vector_type(4))) float f32x4;

// Problem constants
constexpr int DIM_ = 1024;
constexpr int H_   = 16;
constexpr int D_   = 64;
constexpr int HID_ = 1024;
constexpr int N_   = 2;
constexpr int T_   = 1024;
constexpr int MTOT = N_ * T_;   // 2048

// scan chunking
constexpr int L_  = 64;
constexpr int C_  = T_ / L_;    // 16
constexpr int CH  = 32;

__device__ __forceinline__ unsigned short f2bf(float f) {
    __hip_bfloat16 h = __float2bfloat16(f);
    unsigned short u; __builtin_memcpy(&u, &h, 2); return u;
}

__device__ __forceinline__ void gload16(const void* g, void* l) {
    __builtin_amdgcn_global_load_lds(
        (const __attribute__((address_space(1))) void*)g,
        (__attribute__((address_space(3))) void*)l, 16, 0, 0);
}

// ---------------------------------------------------------------------------
// fp32 -> bf16 conversion for x, key_w, vq_w, out_w (one fused launch)
// blocks: [0,2048) x -> Xb ; [2048,3072) key_w -> Wb ; [3072,5120) vq_w -> Wb+1M ;
//         [5120,6144) out_w -> OWb.  4 elems/thread.
// ---------------------------------------------------------------------------
__global__ __launch_bounds__(256) void cvt_all(
    const float* __restrict__ x,  const float* __restrict__ kw,
    const float* __restrict__ vq, const float* __restrict__ ow,
    unsigned short* __restrict__ Xb, unsigned short* __restrict__ Wb,
    unsigned short* __restrict__ OWb)
{
    int b = blockIdx.x;
    const float* src; unsigned short* dst; int off;
    if      (b < 2048) { src = x;  dst = Xb;                 off = b; }
    else if (b < 3072) { src = kw; dst = Wb;                 off = b - 2048; }
    else if (b < 5120) { src = vq; dst = Wb + 1024 * 1024;   off = b - 3072; }
    else               { src = ow; dst = OWb;                off = b - 5120; }
    size_t i = ((size_t)off * 256 + threadIdx.x) * 4;
    float4 v = *(const float4*)&src[i];
    ushort4 o = { f2bf(v.x), f2bf(v.y), f2bf(v.z), f2bf(v.w) };
    *(ushort4*)&dst[i] = o;
}

// ---------------------------------------------------------------------------
// bf16 MFMA GEMM core: C[m,n] = sum_k A[m,k]*B[n,k]  (A,B row-major bf16, K=1024)
// 128x128 tile, BK=32, 256 thr = 4 waves (2x2 of 64x64), 16x16x32 MFMA.
// LDS tiles [128][32] bf16, linear dest for global_load_lds; bank-conflict-free
// reads via chunk swizzle p = c ^ ((row>>1)&3) applied to BOTH the global
// source (staging) and the ds_read address (rule #21).
// ---------------------------------------------------------------------------
#define GEMM_BODY(EPILOGUE)                                                          \
    __shared__ unsigned short As[128 * 32];                                          \
    __shared__ unsigned short Bs[128 * 32];                                          \
    const int tid = threadIdx.x, w = tid >> 6, lane = tid & 63;                      \
    const int wm = w >> 1, wn = w & 1;                                               \
    const int M0 = blockIdx.y * 128, N0 = blockIdx.x * 128;                          \
    const int srow = w * 32 + (lane >> 2);                                           \
    const int kA = (((lane & 3) ^ ((srow >> 1) & 3)) * 8);                           \
    const unsigned short* gA = Ab + (size_t)(M0 + srow) * DIM_ + kA;                 \
    const unsigned short* gB = Bb + (size_t)(N0 + srow) * DIM_ + kA;                 \
    char* lA = (char*)As + w * 2048;                                                 \
    char* lB = (char*)Bs + w * 2048;                                                 \
    const int fr = lane & 15, fc = lane >> 4;                                        \
    const int p  = fc ^ ((fr >> 1) & 3);                                             \
    const int aoff = (wm * 64 + fr) * 64 + p * 16;                                   \
    const int boff = (wn * 64 + fr) * 64 + p * 16;                                   \
    f32x4 acc[4][4] = {};                                                            \
    for (int k0 = 0; k0 < DIM_; k0 += 32) {                                          \
        __syncthreads();                                                             \
        gload16(gA + k0,             lA);                                            \
        gload16(gA + k0 + 16 * DIM_, lA + 1024);                                     \
        gload16(gB + k0,             lB);                                            \
        gload16(gB + k0 + 16 * DIM_, lB + 1024);                                     \
        __syncthreads();                                                             \
        short8 a4[4], b4[4];                                                         \
        _Pragma("unroll")                                                            \
        for (int i = 0; i < 4; ++i) {                                                \
            a4[i] = *(const short8*)((const char*)As + aoff + i * 1024);             \
            b4[i] = *(const short8*)((const char*)Bs + boff + i * 1024);             \
        }                                                                            \
        _Pragma("unroll")                                                            \
        for (int mi = 0; mi < 4; ++mi)                                               \
            _Pragma("unroll")                                                        \
            for (int ni = 0; ni < 4; ++ni)                                           \
                acc[mi][ni] = __builtin_amdgcn_mfma_f32_16x16x32_bf16(               \
                    a4[mi], b4[ni], acc[mi][ni], 0, 0, 0);                           \
    }                                                                                \
    const int cm = M0 + wm * 64 + fc * 4;                                            \
    const int cn = N0 + wn * 64 + fr;                                                \
    EPILOGUE

__global__ __launch_bounds__(256) void gemm_qkv_mfma(
    const unsigned short* __restrict__ Ab,   // Xb [2048][1024]
    const unsigned short* __restrict__ Bb,   // Wb [3072][1024]
    const float* __restrict__ key_b,
    float* __restrict__ Kb, float* __restrict__ Vb, float* __restrict__ Qb)
{
    GEMM_BODY(
        if (N0 < HID_) {
            _Pragma("unroll")
            for (int ni = 0; ni < 4; ++ni) {
                float bias = key_b[cn + ni * 16];
                _Pragma("unroll")
                for (int mi = 0; mi < 4; ++mi)
                    _Pragma("unroll")
                    for (int r = 0; r < 4; ++r) {
                        float vv = acc[mi][ni][r] + bias;
                        Kb[(size_t)(cm + mi * 16 + r) * HID_ + cn + ni * 16] =
                            1.f / (1.f + __expf(-vv));
                    }
            }
        } else if (N0 < 2 * HID_) {
            _Pragma("unroll")
            for (int ni = 0; ni < 4; ++ni)
                _Pragma("unroll")
                for (int mi = 0; mi < 4; ++mi)
                    _Pragma("unroll")
                    for (int r = 0; r < 4; ++r)
                        Vb[(size_t)(cm + mi * 16 + r) * HID_ + cn + ni * 16 - HID_] =
                            acc[mi][ni][r];
        } else {
            _Pragma("unroll")
            for (int ni = 0; ni < 4; ++ni)
                _Pragma("unroll")
                for (int mi = 0; mi < 4; ++mi)
                    _Pragma("unroll")
                    for (int r = 0; r < 4; ++r)
                        Qb[(size_t)(cm + mi * 16 + r) * HID_ + cn + ni * 16 - 2 * HID_] =
                            acc[mi][ni][r];
        }
    )
}

__global__ __launch_bounds__(256) void gemm_out_mfma(
    const unsigned short* __restrict__ Ab,   // Hb bf16 [2048][1024]
    const unsigned short* __restrict__ Bb,   // OWb bf16 [1024][1024]
    const float* __restrict__ out_b,
    float* __restrict__ Out)
{
    GEMM_BODY(
        _Pragma("unroll")
        for (int ni = 0; ni < 4; ++ni) {
            float bias = out_b[cn + ni * 16];
            _Pragma("unroll")
            for (int mi = 0; mi < 4; ++mi)
                _Pragma("unroll")
                for (int r = 0; r < 4; ++r)
                    Out[(size_t)(cm + mi * 16 + r) * DIM_ + cn + ni * 16] =
                        acc[mi][ni][r] + bias;
        }
    )
}

// ---------------------------------------------------------------------------
// Scan phase 1: per (n,h,c) chunk from zero state -> B_c (Sbuf), P_c (Pbuf)
// ---------------------------------------------------------------------------
__global__ __launch_bounds__(256) void scan_phase1(
    const float* __restrict__ Kb,
    const float* __restrict__ Vb,
    float* __restrict__ Sbuf,
    float* __restrict__ Pbuf)
{
    __shared__ float sk[CH][64];
    __shared__ float sv[CH][64];

    const int tid  = threadIdx.x;
    const int w    = tid >> 6;
    const int lane = tid & 63;
    const int c    = blockIdx.x % C_;
    const int head = blockIdx.x / C_;
    const int n = head >> 4, h = head & 15;
    const size_t base = ((size_t)n * T_) * HID_ + (size_t)h * 64;

    float kv[16], pr[16];
    #pragma unroll
    for (int i = 0; i < 16; ++i) { kv[i] = 0.f; pr[i] = 1.f; }

    for (int t0 = c * L_; t0 < (c + 1) * L_; t0 += CH) {
        __syncthreads();
        #pragma unroll
        for (int i = 0; i < CH * 64 / 256; ++i) {
            int idx = tid + i * 256;
            int tl = idx >> 6, d = idx & 63;
            size_t g = base + (size_t)(t0 + tl) * HID_ + d;
            sk[tl][d] = Kb[g];
            sv[tl][d] = Vb[g];
        }
        __syncthreads();

        for (int tl = 0; tl < CH; ++tl) {
            float v = sv[tl][lane];
            #pragma unroll
            for (int i4 = 0; i4 < 4; ++i4) {
                float4 k4 = *(const float4*)&sk[tl][w * 16 + i4 * 4];
                float ks[4] = {k4.x, k4.y, k4.z, k4.w};
                #pragma unroll
                for (int j = 0; j < 4; ++j) {
                    int i = i4 * 4 + j;
                    kv[i] = ks[j] * kv[i] + (1.f - ks[j]) * v;
                    pr[i] *= ks[j];
                }
            }
        }
    }

    const size_t sidx = ((size_t)(head * C_ + c)) * (D_ * D_) + (size_t)(w * 16) * D_ + lane;
    #pragma unroll
    for (int i = 0; i < 16; ++i) Sbuf[sidx + (size_t)i * D_] = kv[i];
    if (lane == 0) {
        const size_t pidx = (size_t)(head * C_ + c) * D_ + w * 16;
        #pragma unroll
        for (int i = 0; i < 16; ++i) Pbuf[pidx + i] = pr[i];
    }
}

// ---------------------------------------------------------------------------
// Scan phase 2: serial combine; Sbuf slot c overwritten with S_init(c)
// ---------------------------------------------------------------------------
__global__ __launch_bounds__(256) void scan_combine(
    float* __restrict__ Sbuf,
    const float* __restrict__ Pbuf)
{
    const int tid  = threadIdx.x;
    const int w    = tid >> 6;
    const int lane = tid & 63;
    const int head = blockIdx.x;

    float S[16];
    #pragma unroll
    for (int i = 0; i < 16; ++i) S[i] = 0.f;

    for (int c = 0; c < C_; ++c) {
        const size_t sidx = ((size_t)(head * C_ + c)) * (D_ * D_) + (size_t)(w * 16) * D_ + lane;
        const size_t pidx = (size_t)(head * C_ + c) * D_ + w * 16;
        #pragma unroll
        for (int i = 0; i < 16; ++i) {
            float B  = Sbuf[sidx + (size_t)i * D_];
            float pp = Pbuf[pidx + i];
            Sbuf[sidx + (size_t)i * D_] = S[i];
            S[i] = pp * S[i] + B;
        }
    }
}

// ---------------------------------------------------------------------------
// Scan phase 3: rescan from S_init(c), emit h as bf16 into Hb
// ---------------------------------------------------------------------------
__global__ __launch_bounds__(256) void scan_phase3(
    const float* __restrict__ Kb,
    const float* __restrict__ Vb,
    const float* __restrict__ Qb,
    const float* __restrict__ Sbuf,
    unsigned short* __restrict__ Hb)
{
    __shared__ float sk[CH][64];
    __shared__ float sv[CH][64];
    __shared__ float sq[CH][64];
    __shared__ float hp[4][CH][64];

    const int tid  = threadIdx.x;
    const int w    = tid >> 6;
    const int lane = tid & 63;
    const int c    = blockIdx.x % C_;
    const int head = blockIdx.x / C_;
    const int n = head >> 4, h = head & 15;
    const size_t base = ((size_t)n * T_) * HID_ + (size_t)h * 64;

    float kv[16];
    const size_t sidx = ((size_t)(head * C_ + c)) * (D_ * D_) + (size_t)(w * 16) * D_ + lane;
    #pragma unroll
    for (int i = 0; i < 16; ++i) kv[i] = Sbuf[sidx + (size_t)i * D_];

    for (int t0 = c * L_; t0 < (c + 1) * L_; t0 += CH) {
        __syncthreads();
        #pragma unroll
        for (int i = 0; i < CH * 64 / 256; ++i) {
            int idx = tid + i * 256;
            int tl = idx >> 6, d = idx & 63;
            size_t g = base + (size_t)(t0 + tl) * HID_ + d;
            sk[tl][d] = Kb[g];
            sv[tl][d] = Vb[g];
            sq[tl][d] = Qb[g];
        }
        __syncthreads();

        for (int tl = 0; tl < CH; ++tl) {
            float part = 0.f;
            float v = sv[tl][lane];
            #pragma unroll
            for (int i4 = 0; i4 < 4; ++i4) {
                float4 k4 = *(const float4*)&sk[tl][w * 16 + i4 * 4];
                float4 q4 = *(const float4*)&sq[tl][w * 16 + i4 * 4];
                float ks[4] = {k4.x, k4.y, k4.z, k4.w};
                float qs[4] = {q4.x, q4.y, q4.z, q4.w};
                #pragma unroll
                for (int j = 0; j < 4; ++j) {
                    int i = i4 * 4 + j;
                    kv[i] = ks[j] * kv[i] + (1.f - ks[j]) * v;
                    part += qs[j] * kv[i];
                }
            }
            hp[w][tl][lane] = part;
        }
        __syncthreads();

        #pragma unroll
        for (int i = 0; i < CH * 64 / 256; ++i) {
            int idx = tid + i * 256;
            int tl = idx >> 6, e = idx & 63;
            float s = hp[0][tl][e] + hp[1][tl][e] + hp[2][tl][e] + hp[3][tl][e];
            Hb[base + (size_t)(t0 + tl) * HID_ + e] = f2bf(s);
        }
    }
}

// ---------------------------------------------------------------------------
extern "C" void kernel_launch(void* const* d_in, const int* in_sizes, int n_in,
                              void* d_out, int out_size, void* d_ws, size_t ws_size,
                              hipStream_t stream)
{
    const float* x     = (const float*)d_in[0];
    const float* key_w = (const float*)d_in[1];
    const float* key_b = (const float*)d_in[2];
    const float* vq_w  = (const float*)d_in[3];
    const float* out_w = (const float*)d_in[4];
    const float* out_b = (const float*)d_in[5];
    float* out = (float*)d_out;

    const size_t MH = (size_t)MTOT * HID_;   // 2M elements
    float* Kb   = (float*)d_ws;
    float* Vb   = Kb + MH;
    float* Qb   = Vb + MH;
    float* Sbuf = Qb + MH;                          // 2M fp32
    float* Pbuf = Sbuf + (size_t)N_ * H_ * C_ * D_ * D_;  // 32K fp32
    unsigned short* Xb  = (unsigned short*)(Pbuf + (size_t)N_ * H_ * C_ * D_);
    unsigned short* Wb  = Xb + MH;                  // 3M bf16
    unsigned short* OWb = Wb + 3 * 1024 * 1024;
    unsigned short* Hb  = OWb + 1024 * 1024;

    cvt_all<<<6144, 256, 0, stream>>>(x, key_w, vq_w, out_w, Xb, Wb, OWb);
    gemm_qkv_mfma<<<dim3(24, 16), 256, 0, stream>>>(Xb, Wb, key_b, Kb, Vb, Qb);
    scan_phase1<<<N_ * H_ * C_, 256, 0, stream>>>(Kb, Vb, Sbuf, Pbuf);
    scan_combine<<<N_ * H_, 256, 0, stream>>>(Sbuf, Pbuf);
    scan_phase3<<<N_ * H_ * C_, 256, 0, stream>>>(Kb, Vb, Qb, Sbuf, Hb);
    gemm_out_mfma<<<dim3(8, 16), 256, 0, stream>>>(Hb, OWb, out_b, out);
}

// Round 4
// 101.387 us; speedup vs baseline: 4.4423x; 1.0772x over previous
//
#include <hip/hip_runtime.h>
#include <hip/hip_bf16.h>

typedef __attribute__((ext_vector_type(8))) short short8;
typedef __attribute__((ext_vector_type(4))) float f32x4;

// Problem constants
constexpr int DIM_ = 1024;
constexpr int H_   = 16;
constexpr int D_   = 64;
constexpr int HID_ = 1024;
constexpr int N_   = 2;
constexpr int T_   = 1024;
constexpr int MTOT = N_ * T_;   // 2048

// scan chunking
constexpr int LC = 32;           // chunk length
constexpr int NC = T_ / LC;      // 32 chunks
constexpr int NHEAD = N_ * H_;   // 32

__device__ __forceinline__ unsigned short f2bf(float f) {
    __hip_bfloat16 h = __float2bfloat16(f);
    unsigned short u; __builtin_memcpy(&u, &h, 2); return u;
}
__device__ __forceinline__ float bf2f(unsigned short u) {
    unsigned int b = ((unsigned int)u) << 16;
    float f; __builtin_memcpy(&f, &b, 4); return f;
}

__device__ __forceinline__ void gload16(const void* g, void* l) {
    __builtin_amdgcn_global_load_lds(
        (const __attribute__((address_space(1))) void*)g,
        (__attribute__((address_space(3))) void*)l, 16, 0, 0);
}

// ---------------------------------------------------------------------------
// fp32 -> bf16 conversion for x, key_w, vq_w, out_w
// ---------------------------------------------------------------------------
__global__ __launch_bounds__(256) void cvt_all(
    const float* __restrict__ x,  const float* __restrict__ kw,
    const float* __restrict__ vq, const float* __restrict__ ow,
    unsigned short* __restrict__ Xb, unsigned short* __restrict__ Wb,
    unsigned short* __restrict__ OWb)
{
    int b = blockIdx.x;
    const float* src; unsigned short* dst; int off;
    if      (b < 2048) { src = x;  dst = Xb;                 off = b; }
    else if (b < 3072) { src = kw; dst = Wb;                 off = b - 2048; }
    else if (b < 5120) { src = vq; dst = Wb + 1024 * 1024;   off = b - 3072; }
    else               { src = ow; dst = OWb;                off = b - 5120; }
    size_t i = ((size_t)off * 256 + threadIdx.x) * 4;
    float4 v = *(const float4*)&src[i];
    ushort4 o = { f2bf(v.x), f2bf(v.y), f2bf(v.z), f2bf(v.w) };
    *(ushort4*)&dst[i] = o;
}

// ---------------------------------------------------------------------------
// bf16 MFMA GEMM core (128x128 tile, BK=32, swizzled LDS; see R2 notes)
// ---------------------------------------------------------------------------
#define GEMM_BODY(EPILOGUE)                                                          \
    __shared__ unsigned short As[128 * 32];                                          \
    __shared__ unsigned short Bs[128 * 32];                                          \
    const int tid = threadIdx.x, w = tid >> 6, lane = tid & 63;                      \
    const int wm = w >> 1, wn = w & 1;                                               \
    const int M0 = blockIdx.y * 128, N0 = blockIdx.x * 128;                          \
    const int srow = w * 32 + (lane >> 2);                                           \
    const int kA = (((lane & 3) ^ ((srow >> 1) & 3)) * 8);                           \
    const unsigned short* gA = Ab + (size_t)(M0 + srow) * DIM_ + kA;                 \
    const unsigned short* gB = Bb + (size_t)(N0 + srow) * DIM_ + kA;                 \
    char* lA = (char*)As + w * 2048;                                                 \
    char* lB = (char*)Bs + w * 2048;                                                 \
    const int fr = lane & 15, fc = lane >> 4;                                        \
    const int p  = fc ^ ((fr >> 1) & 3);                                             \
    const int aoff = (wm * 64 + fr) * 64 + p * 16;                                   \
    const int boff = (wn * 64 + fr) * 64 + p * 16;                                   \
    f32x4 acc[4][4] = {};                                                            \
    for (int k0 = 0; k0 < DIM_; k0 += 32) {                                          \
        __syncthreads();                                                             \
        gload16(gA + k0,             lA);                                            \
        gload16(gA + k0 + 16 * DIM_, lA + 1024);                                     \
        gload16(gB + k0,             lB);                                            \
        gload16(gB + k0 + 16 * DIM_, lB + 1024);                                     \
        __syncthreads();                                                             \
        short8 a4[4], b4[4];                                                         \
        _Pragma("unroll")                                                            \
        for (int i = 0; i < 4; ++i) {                                                \
            a4[i] = *(const short8*)((const char*)As + aoff + i * 1024);             \
            b4[i] = *(const short8*)((const char*)Bs + boff + i * 1024);             \
        }                                                                            \
        _Pragma("unroll")                                                            \
        for (int mi = 0; mi < 4; ++mi)                                               \
            _Pragma("unroll")                                                        \
            for (int ni = 0; ni < 4; ++ni)                                           \
                acc[mi][ni] = __builtin_amdgcn_mfma_f32_16x16x32_bf16(               \
                    a4[mi], b4[ni], acc[mi][ni], 0, 0, 0);                           \
    }                                                                                \
    const int cm = M0 + wm * 64 + fc * 4;                                            \
    const int cn = N0 + wn * 64 + fr;                                                \
    EPILOGUE

__global__ __launch_bounds__(256) void gemm_qkv_mfma(
    const unsigned short* __restrict__ Ab,   // Xb [2048][1024]
    const unsigned short* __restrict__ Bb,   // Wb [3072][1024]
    const float* __restrict__ key_b,
    float* __restrict__ Kb, float* __restrict__ Vb, float* __restrict__ Qb)
{
    GEMM_BODY(
        if (N0 < HID_) {
            _Pragma("unroll")
            for (int ni = 0; ni < 4; ++ni) {
                float bias = key_b[cn + ni * 16];
                _Pragma("unroll")
                for (int mi = 0; mi < 4; ++mi)
                    _Pragma("unroll")
                    for (int r = 0; r < 4; ++r) {
                        float vv = acc[mi][ni][r] + bias;
                        Kb[(size_t)(cm + mi * 16 + r) * HID_ + cn + ni * 16] =
                            1.f / (1.f + __expf(-vv));
                    }
            }
        } else if (N0 < 2 * HID_) {
            _Pragma("unroll")
            for (int ni = 0; ni < 4; ++ni)
                _Pragma("unroll")
                for (int mi = 0; mi < 4; ++mi)
                    _Pragma("unroll")
                    for (int r = 0; r < 4; ++r)
                        Vb[(size_t)(cm + mi * 16 + r) * HID_ + cn + ni * 16 - HID_] =
                            acc[mi][ni][r];
        } else {
            _Pragma("unroll")
            for (int ni = 0; ni < 4; ++ni)
                _Pragma("unroll")
                for (int mi = 0; mi < 4; ++mi)
                    _Pragma("unroll")
                    for (int r = 0; r < 4; ++r)
                        Qb[(size_t)(cm + mi * 16 + r) * HID_ + cn + ni * 16 - 2 * HID_] =
                            acc[mi][ni][r];
        }
    )
}

__global__ __launch_bounds__(256) void gemm_out_mfma(
    const unsigned short* __restrict__ Ab,   // Hb bf16 [2048][1024]
    const unsigned short* __restrict__ Bb,   // OWb bf16 [1024][1024]
    const float* __restrict__ out_b,
    float* __restrict__ Out)
{
    GEMM_BODY(
        _Pragma("unroll")
        for (int ni = 0; ni < 4; ++ni) {
            float bias = out_b[cn + ni * 16];
            _Pragma("unroll")
            for (int mi = 0; mi < 4; ++mi)
                _Pragma("unroll")
                for (int r = 0; r < 4; ++r)
                    Out[(size_t)(cm + mi * 16 + r) * DIM_ + cn + ni * 16] =
                        acc[mi][ni][r] + bias;
        }
    )
}

// ---------------------------------------------------------------------------
// Scan phase 1 (only scalar pass): per (head, chunk of 32):
//  - scan kv from ZERO state  -> h_intra (bf16, written to Hb)
//  - chunk-end state B_c      -> Sbuf  [head][c][e][d] fp32
//  - chunk decay product P_c  -> Pbuf  [head][c][d]
//  - qa[t,d] = q[t,d]*cumprod_k (incl) -> QAb [head][c][t][d] bf16
// Block: 256 thr = 4 waves; wave w owns d in [w*16,w*16+16); lane = e.
// ---------------------------------------------------------------------------
__global__ __launch_bounds__(256) void scan_phase1(
    const float* __restrict__ Kb,
    const float* __restrict__ Vb,
    const float* __restrict__ Qb,
    float* __restrict__ Sbuf,
    float* __restrict__ Pbuf,
    unsigned short* __restrict__ QAb,
    unsigned short* __restrict__ Hb)
{
    __shared__ float sk[LC][64];
    __shared__ float sv[LC][64];
    __shared__ float sq[LC][64];
    __shared__ float hp[4][16][64];
    __shared__ unsigned short qs[LC][64];

    const int tid  = threadIdx.x;
    const int w    = tid >> 6;
    const int lane = tid & 63;
    const int c    = blockIdx.x & (NC - 1);
    const int head = blockIdx.x >> 5;
    const int n = head >> 4, h = head & 15;
    const size_t base = ((size_t)n * T_) * HID_ + (size_t)h * 64;

    // stage the whole chunk (LC*64 elems, 8 per thread)
    #pragma unroll
    for (int i = 0; i < LC * 64 / 256; ++i) {
        int idx = tid + i * 256;
        int tl = idx >> 6, d = idx & 63;
        size_t g = base + (size_t)(c * LC + tl) * HID_ + d;
        sk[tl][d] = Kb[g];
        sv[tl][d] = Vb[g];
        sq[tl][d] = Qb[g];
    }
    __syncthreads();

    const int dq = w * 16 + (lane & 15);   // the d this lane tracks for qa/P
    float kv[16];
    #pragma unroll
    for (int i = 0; i < 16; ++i) kv[i] = 0.f;
    float pq = 1.f;

    #pragma unroll
    for (int half = 0; half < 2; ++half) {
        for (int tl2 = 0; tl2 < 16; ++tl2) {
            const int tl = half * 16 + tl2;
            float part = 0.f;
            float v = sv[tl][lane];
            #pragma unroll
            for (int i4 = 0; i4 < 4; ++i4) {
                float4 k4 = *(const float4*)&sk[tl][w * 16 + i4 * 4];
                float4 q4 = *(const float4*)&sq[tl][w * 16 + i4 * 4];
                float ks[4] = {k4.x, k4.y, k4.z, k4.w};
                float qs_[4] = {q4.x, q4.y, q4.z, q4.w};
                #pragma unroll
                for (int j = 0; j < 4; ++j) {
                    int i = i4 * 4 + j;
                    kv[i] = ks[j] * kv[i] + (1.f - ks[j]) * v;
                    part += qs_[j] * kv[i];
                }
            }
            hp[w][tl2][lane] = part;
            // qa tracking (replicated across e; lanes<16 own one d each)
            pq *= sk[tl][dq];
            if (lane < 16) qs[tl][dq] = f2bf(sq[tl][dq] * pq);
        }
        __syncthreads();
        // reduce hp over waves, emit h_intra for this half (16 t's)
        #pragma unroll
        for (int i = 0; i < 16 * 64 / 256; ++i) {
            int idx = tid + i * 256;
            int tl2 = idx >> 6, e = idx & 63;
            float s = hp[0][tl2][e] + hp[1][tl2][e] + hp[2][tl2][e] + hp[3][tl2][e];
            Hb[base + (size_t)(c * LC + half * 16 + tl2) * HID_ + e] = f2bf(s);
        }
        __syncthreads();
    }

    // B_c -> Sbuf in [e][d] layout (transposed: row=e, col=d)
    const size_t sbase = (size_t)(head * NC + c) * (D_ * D_);
    #pragma unroll
    for (int i = 0; i < 4; ++i) {
        float4 o = { kv[i * 4 + 0], kv[i * 4 + 1], kv[i * 4 + 2], kv[i * 4 + 3] };
        *(float4*)&Sbuf[sbase + (size_t)lane * D_ + w * 16 + i * 4] = o;
    }
    // P_c
    if (lane < 16) Pbuf[(size_t)(head * NC + c) * D_ + dq] = pq;
    // qa dump (coalesced, 8 ushorts per thread)
    const unsigned short* qsl = &qs[0][0];
    *(short8*)&QAb[(size_t)(head * NC + c) * (LC * 64) + tid * 8] =
        *(const short8*)&qsl[tid * 8];
}

// ---------------------------------------------------------------------------
// Scan phase 2: combine across chunks. grid = 32 heads * 16 e-groups.
// Each thread owns one (e,d) element, serial over c.
// Emits S_init(c) as bf16 into SbB [head][c][e][d] (B-operand for phase 3).
// ---------------------------------------------------------------------------
__global__ __launch_bounds__(256) void scan_combine(
    const float* __restrict__ Sbuf,
    const float* __restrict__ Pbuf,
    unsigned short* __restrict__ SbB)
{
    const int tid  = threadIdx.x;
    const int head = blockIdx.x >> 4;
    const int e    = (blockIdx.x & 15) * 4 + (tid >> 6);
    const int d    = tid & 63;

    float S = 0.f;
    for (int ci = 0; ci < NC; ++ci) {
        const size_t sidx = (size_t)(head * NC + ci) * (D_ * D_) + (size_t)e * D_ + d;
        float B  = Sbuf[sidx];
        float pp = Pbuf[(size_t)(head * NC + ci) * D_ + d];
        SbB[sidx] = f2bf(S);
        S = pp * S + B;
    }
}

// ---------------------------------------------------------------------------
// Scan phase 3 (MFMA): h[t,e] += sum_d qa[t,d] * S_init[e,d]  per (head,chunk).
// One wave per (head,c); 2 t-tiles x 4 e-tiles x 2 k-steps = 16 MFMAs.
// ---------------------------------------------------------------------------
__global__ __launch_bounds__(256) void scan_inter_mfma(
    const unsigned short* __restrict__ QAb,
    const unsigned short* __restrict__ SbB,
    unsigned short* __restrict__ Hb)
{
    const int tid = threadIdx.x, w = tid >> 6, lane = tid & 63;
    const int wid  = blockIdx.x * 4 + w;      // 0..1023
    const int head = wid >> 5, c = wid & 31;
    const int n = head >> 4, h = head & 15;
    const int fr = lane & 15, fc = lane >> 4;

    const unsigned short* qa = QAb + (size_t)(head * NC + c) * (LC * 64);
    const unsigned short* sb = SbB + (size_t)(head * NC + c) * (D_ * D_);

    short8 a[2][2], b[4][2];
    #pragma unroll
    for (int mi = 0; mi < 2; ++mi)
        #pragma unroll
        for (int ks = 0; ks < 2; ++ks)
            a[mi][ks] = *(const short8*)&qa[(mi * 16 + fr) * 64 + fc * 8 + ks * 32];
    #pragma unroll
    for (int ni = 0; ni < 4; ++ni)
        #pragma unroll
        for (int ks = 0; ks < 2; ++ks)
            b[ni][ks] = *(const short8*)&sb[(ni * 16 + fr) * 64 + fc * 8 + ks * 32];

    f32x4 acc[2][4] = {};
    #pragma unroll
    for (int mi = 0; mi < 2; ++mi)
        #pragma unroll
        for (int ni = 0; ni < 4; ++ni)
            #pragma unroll
            for (int ks = 0; ks < 2; ++ks)
                acc[mi][ni] = __builtin_amdgcn_mfma_f32_16x16x32_bf16(
                    a[mi][ks], b[ni][ks], acc[mi][ni], 0, 0, 0);

    #pragma unroll
    for (int mi = 0; mi < 2; ++mi)
        #pragma unroll
        for (int ni = 0; ni < 4; ++ni)
            #pragma unroll
            for (int r = 0; r < 4; ++r) {
                int t = c * LC + mi * 16 + fc * 4 + r;
                size_t g = ((size_t)n * T_ + t) * HID_ + h * 64 + ni * 16 + fr;
                Hb[g] = f2bf(bf2f(Hb[g]) + acc[mi][ni][r]);
            }
}

// ---------------------------------------------------------------------------
extern "C" void kernel_launch(void* const* d_in, const int* in_sizes, int n_in,
                              void* d_out, int out_size, void* d_ws, size_t ws_size,
                              hipStream_t stream)
{
    const float* x     = (const float*)d_in[0];
    const float* key_w = (const float*)d_in[1];
    const float* key_b = (const float*)d_in[2];
    const float* vq_w  = (const float*)d_in[3];
    const float* out_w = (const float*)d_in[4];
    const float* out_b = (const float*)d_in[5];
    float* out = (float*)d_out;

    const size_t MH = (size_t)MTOT * HID_;   // 2M elements
    float* Kb   = (float*)d_ws;                                   // 8 MB
    float* Vb   = Kb + MH;                                        // 8 MB
    float* Qb   = Vb + MH;                                        // 8 MB
    float* Sbuf = Qb + MH;                                        // 16 MB (32*32*4096 f32)
    float* Pbuf = Sbuf + (size_t)NHEAD * NC * D_ * D_;            // 256 KB
    unsigned short* SbB = (unsigned short*)(Pbuf + (size_t)NHEAD * NC * D_);  // 8 MB
    unsigned short* QAb = SbB + (size_t)NHEAD * NC * D_ * D_;     // 4 MB
    unsigned short* Xb  = QAb + (size_t)NHEAD * NC * LC * D_;     // 4 MB
    unsigned short* Wb  = Xb + MH;                                // 6 MB
    unsigned short* OWb = Wb + 3 * 1024 * 1024;                   // 2 MB
    unsigned short* Hb  = OWb + 1024 * 1024;                      // 4 MB

    cvt_all<<<6144, 256, 0, stream>>>(x, key_w, vq_w, out_w, Xb, Wb, OWb);
    gemm_qkv_mfma<<<dim3(24, 16), 256, 0, stream>>>(Xb, Wb, key_b, Kb, Vb, Qb);
    scan_phase1<<<NHEAD * NC, 256, 0, stream>>>(Kb, Vb, Qb, Sbuf, Pbuf, QAb, Hb);
    scan_combine<<<NHEAD * 16, 256, 0, stream>>>(Sbuf, Pbuf, SbB);
    scan_inter_mfma<<<NHEAD * NC / 4, 256, 0, stream>>>(QAb, SbB, Hb);
    gemm_out_mfma<<<dim3(8, 16), 256, 0, stream>>>(Hb, OWb, out_b, out);
}